// Round 1
// baseline (1539.141 us; speedup 1.0000x reference)
//
#include <hip/hip_runtime.h>

// 2-layer GCN + mean-pool + linear head for MI355X (gfx950).
// Pipeline:
//   1. degrees (atomic count) -> rsqrt(max(deg,1)) in place
//   2. scatter1: agg1[dst] += feats[src] * (w_e * dinv_out[src])   [E x 64 atomics]
//   3. fused:    x2[n] = (leaky((agg1[n]*dinv_in[n]) @ W1) * dinv_out[n]) @ W2
//   4. scatter2: agg2[dst] += x2[src] * w_e                        [E x 128 atomics]
//   5. pool+head: out[g] = ((mean_n leaky(agg2[n]*dinv_in[n])) @ W_lin) @ W_cls

constexpr int NPG = 128;   // nodes per graph
constexpr int F0  = 64;    // in_feats
constexpr int F1  = 256;   // hidden
constexpr int F2  = 128;   // readout

__global__ void k_degree(const int* __restrict__ src, const int* __restrict__ dst,
                         float* __restrict__ deg_out, float* __restrict__ deg_in, int E) {
    int e = blockIdx.x * blockDim.x + threadIdx.x;
    if (e < E) {
        atomicAdd(&deg_out[src[e]], 1.0f);
        atomicAdd(&deg_in[dst[e]], 1.0f);
    }
}

__global__ void k_finalize_deg(float* __restrict__ a, float* __restrict__ b, int N) {
    int i = blockIdx.x * blockDim.x + threadIdx.x;
    if (i < N) {
        a[i] = rsqrtf(fmaxf(a[i], 1.0f));
        b[i] = rsqrtf(fmaxf(b[i], 1.0f));
    }
}

// one thread per (edge, feature): 64 feats
__global__ void k_scatter1(const float* __restrict__ feats, const float* __restrict__ we,
                           const int* __restrict__ src, const int* __restrict__ dst,
                           const float* __restrict__ dinv_out, float* __restrict__ agg1,
                           unsigned E) {
    unsigned gid = blockIdx.x * 256u + threadIdx.x;
    unsigned e = gid >> 6;
    unsigned d = gid & 63u;
    if (e < E) {
        int s = src[e], t = dst[e];
        float w = we[e] * dinv_out[s];
        atomicAdd(&agg1[(size_t)t * F0 + d], feats[(size_t)s * F0 + d] * w);
    }
}

// per-node fused: layer1 GEMM + leaky + layer2 pre-scale + layer2 projection
__global__ void __launch_bounds__(128) k_fused(const float* __restrict__ agg1,
                        const float* __restrict__ dinv_in,
                        const float* __restrict__ dinv_out,
                        const float* __restrict__ W1,   // [64][256]
                        const float* __restrict__ W2,   // [256][128]
                        float* __restrict__ x2) {
    int n = blockIdx.x;
    int t = threadIdx.x;  // 0..127
    __shared__ float a[F0];
    __shared__ float h[F1];
    float din  = dinv_in[n];
    float dout = dinv_out[n];
    if (t < F0) a[t] = agg1[(size_t)n * F0 + t] * din;
    __syncthreads();
    float acc0 = 0.f, acc1 = 0.f;
#pragma unroll
    for (int k = 0; k < F0; ++k) {
        float av = a[k];
        acc0 = fmaf(av, W1[k * F1 + t], acc0);
        acc1 = fmaf(av, W1[k * F1 + t + 128], acc1);
    }
    acc0 = (acc0 >= 0.f) ? acc0 : 0.01f * acc0;   // leaky
    acc1 = (acc1 >= 0.f) ? acc1 : 0.01f * acc1;
    h[t]       = acc0 * dout;                      // layer-2 src-scale folded in
    h[t + 128] = acc1 * dout;
    __syncthreads();
    float acc = 0.f;
    for (int k = 0; k < F1; ++k) acc = fmaf(h[k], W2[k * F2 + t], acc);
    x2[(size_t)n * F2 + t] = acc;
}

// one thread per (edge, feature): 128 feats
__global__ void k_scatter2(const float* __restrict__ x2, const float* __restrict__ we,
                           const int* __restrict__ src, const int* __restrict__ dst,
                           float* __restrict__ agg2, unsigned E) {
    unsigned gid = blockIdx.x * 256u + threadIdx.x;
    unsigned e = gid >> 7;
    unsigned d = gid & 127u;
    if (e < E) {
        int s = src[e], t = dst[e];
        atomicAdd(&agg2[(size_t)t * F2 + d], x2[(size_t)s * F2 + d] * we[e]);
    }
}

// one block per graph: dst-scale + leaky + mean pool + 128->64->16 head
__global__ void __launch_bounds__(128) k_pool_head(const float* __restrict__ agg2,
                            const float* __restrict__ dinv_in,
                            const float* __restrict__ Wlin,  // [128][64]
                            const float* __restrict__ Wcls,  // [64][16]
                            float* __restrict__ out) {
    int g = blockIdx.x;
    int t = threadIdx.x;  // 0..127
    __shared__ float p[F2];
    __shared__ float tj[64];
    float acc = 0.f;
    int base = g * NPG;
#pragma unroll 4
    for (int i = 0; i < NPG; ++i) {
        float v = agg2[(size_t)(base + i) * F2 + t] * dinv_in[base + i];
        v = (v >= 0.f) ? v : 0.01f * v;  // leaky
        acc += v;
    }
    p[t] = acc * (1.0f / NPG);
    __syncthreads();
    if (t < 64) {
        float s = 0.f;
#pragma unroll
        for (int d = 0; d < F2; ++d) s = fmaf(p[d], Wlin[d * 64 + t], s);
        tj[t] = s;
    }
    __syncthreads();
    if (t < 16) {
        float s = 0.f;
#pragma unroll
        for (int j = 0; j < 64; ++j) s = fmaf(tj[j], Wcls[j * 16 + t], s);
        out[g * 16 + t] = s;
    }
}

extern "C" void kernel_launch(void* const* d_in, const int* in_sizes, int n_in,
                              void* d_out, int out_size, void* d_ws, size_t ws_size,
                              hipStream_t stream) {
    const float* feats = (const float*)d_in[0];
    const float* we    = (const float*)d_in[1];
    const float* W1    = (const float*)d_in[2];
    const float* W2    = (const float*)d_in[3];
    const float* Wlin  = (const float*)d_in[4];
    const float* Wcls  = (const float*)d_in[5];
    const int*   src   = (const int*)d_in[6];
    const int*   dst   = (const int*)d_in[7];

    const int N = in_sizes[0] / F0;      // 131072
    const unsigned E = (unsigned)in_sizes[1];  // 1048576
    const int G = N / NPG;               // 1024

    float* out = (float*)d_out;

    // workspace layout: dinv_out[N] | dinv_in[N] | region1[N*128] | x2[N*128]
    float* dinv_out = (float*)d_ws;
    float* dinv_in  = dinv_out + N;
    float* region1  = dinv_in + N;        // agg1 (N*64) then reused as agg2 (N*128)
    float* agg1     = region1;
    float* agg2     = region1;
    float* x2       = region1 + (size_t)N * F2;

    hipMemsetAsync(dinv_out, 0, (size_t)2 * N * sizeof(float), stream);
    hipMemsetAsync(agg1, 0, (size_t)N * F0 * sizeof(float), stream);

    k_degree<<<(E + 255) / 256, 256, 0, stream>>>(src, dst, dinv_out, dinv_in, (int)E);
    k_finalize_deg<<<(N + 255) / 256, 256, 0, stream>>>(dinv_out, dinv_in, N);

    k_scatter1<<<(unsigned)(((size_t)E * F0 + 255) / 256), 256, 0, stream>>>(
        feats, we, src, dst, dinv_out, agg1, E);

    k_fused<<<N, 128, 0, stream>>>(agg1, dinv_in, dinv_out, W1, W2, x2);

    hipMemsetAsync(agg2, 0, (size_t)N * F2 * sizeof(float), stream);
    k_scatter2<<<(unsigned)(((size_t)E * F2 + 255) / 256), 256, 0, stream>>>(
        x2, we, src, dst, agg2, E);

    k_pool_head<<<G, 128, 0, stream>>>(agg2, dinv_in, Wlin, Wcls, out);
}

// Round 2
// 1126.568 us; speedup vs baseline: 1.3662x; 1.3662x over previous
//
#include <hip/hip_runtime.h>

// 2-layer GCN + mean-pool + linear head for MI355X (gfx950).
// R1 change: k_fused rewritten as node-tiled register-blocked double GEMM
// (32 nodes/block) to amortize W1/W2 reads (was: 192 KB of weights re-read
// per NODE -> ~25 GB L2 traffic -> 820 us L2-bound).

constexpr int NPG = 128;   // nodes per graph
constexpr int F0  = 64;    // in_feats
constexpr int F1  = 256;   // hidden
constexpr int F2  = 128;   // readout
constexpr int BM  = 32;    // nodes per fused block
constexpr int LDA = BM + 4; // LDS leading dim (float4-aligned padding)

__device__ __forceinline__ float leaky(float x) {
    return (x >= 0.f) ? x : 0.01f * x;
}

__global__ void k_degree(const int* __restrict__ src, const int* __restrict__ dst,
                         float* __restrict__ deg_out, float* __restrict__ deg_in, int E) {
    int e = blockIdx.x * blockDim.x + threadIdx.x;
    if (e < E) {
        atomicAdd(&deg_out[src[e]], 1.0f);
        atomicAdd(&deg_in[dst[e]], 1.0f);
    }
}

__global__ void k_finalize_deg(float* __restrict__ a, float* __restrict__ b, int N) {
    int i = blockIdx.x * blockDim.x + threadIdx.x;
    if (i < N) {
        a[i] = rsqrtf(fmaxf(a[i], 1.0f));
        b[i] = rsqrtf(fmaxf(b[i], 1.0f));
    }
}

// one thread per (edge, feature): 64 feats
__global__ void k_scatter1(const float* __restrict__ feats, const float* __restrict__ we,
                           const int* __restrict__ src, const int* __restrict__ dst,
                           const float* __restrict__ dinv_out, float* __restrict__ agg1,
                           unsigned E) {
    unsigned gid = blockIdx.x * 256u + threadIdx.x;
    unsigned e = gid >> 6;
    unsigned d = gid & 63u;
    if (e < E) {
        int s = src[e], t = dst[e];
        float w = we[e] * dinv_out[s];
        atomicAdd(&agg1[(size_t)t * F0 + d], feats[(size_t)s * F0 + d] * w);
    }
}

// Fused: x2 = (leaky((agg1*dinv_in) @ W1) * dinv_out) @ W2
// Block: 32 nodes, 256 threads. LDS: aT[64][36] + hT[256][36] = 42.2 KB.
__global__ void __launch_bounds__(256, 2) k_fused2(
        const float* __restrict__ agg1,
        const float* __restrict__ dinv_in,
        const float* __restrict__ dinv_out,
        const float* __restrict__ W1,   // [64][256]
        const float* __restrict__ W2,   // [256][128]
        float* __restrict__ x2) {
    __shared__ float aT[F0][LDA];   // A transposed, XOR-swizzled on node index
    __shared__ float hT[F1][LDA];   // H transposed, XOR-swizzled on node index
    const int t = threadIdx.x;
    const int base = blockIdx.x * BM;

    // ---- phase 0: load A tile (32 nodes x 64 feats), scale by dinv_in, transpose
    {
        const int nn = t >> 3;            // 0..31 node
        const int f0 = (t & 7) * 8;       // 0..56 feature base
        const float4* p = (const float4*)(agg1 + (size_t)(base + nn) * F0 + f0);
        float4 v0 = p[0], v1 = p[1];
        const float din = dinv_in[base + nn];
        float v[8] = {v0.x, v0.y, v0.z, v0.w, v1.x, v1.y, v1.z, v1.w};
#pragma unroll
        for (int j = 0; j < 8; ++j) {
            int f = f0 + j;
            aT[f][nn ^ (((f >> 3) & 7) << 2)] = v[j] * din;
        }
    }
    __syncthreads();

    // ---- phase 1: H[32][256] = leaky(A @ W1) * dout
    const int cg = t & 31, ng = t >> 5;
    const int c0 = cg * 8;     // 8 columns of 256
    const int n0 = ng * 4;     // 4 nodes of 32
    float acc[4][8];
#pragma unroll
    for (int i = 0; i < 4; ++i)
#pragma unroll
        for (int j = 0; j < 8; ++j) acc[i][j] = 0.f;

#pragma unroll 8
    for (int k = 0; k < F0; ++k) {
        const float4 a = *(const float4*)&aT[k][n0 ^ (((k >> 3) & 7) << 2)];
        const float4 w0 = *(const float4*)&W1[k * F1 + c0];
        const float4 w1 = *(const float4*)&W1[k * F1 + c0 + 4];
        const float an[4] = {a.x, a.y, a.z, a.w};
        const float wc[8] = {w0.x, w0.y, w0.z, w0.w, w1.x, w1.y, w1.z, w1.w};
#pragma unroll
        for (int i = 0; i < 4; ++i)
#pragma unroll
            for (int j = 0; j < 8; ++j)
                acc[i][j] = fmaf(an[i], wc[j], acc[i][j]);
    }

    float dsc[4];
#pragma unroll
    for (int i = 0; i < 4; ++i) dsc[i] = dinv_out[base + n0 + i];
#pragma unroll
    for (int j = 0; j < 8; ++j) {
        const int c = c0 + j;
        float4 v;
        v.x = leaky(acc[0][j]) * dsc[0];
        v.y = leaky(acc[1][j]) * dsc[1];
        v.z = leaky(acc[2][j]) * dsc[2];
        v.w = leaky(acc[3][j]) * dsc[3];
        *(float4*)&hT[c][n0 ^ (((c >> 3) & 7) << 2)] = v;
    }
    __syncthreads();

    // ---- phase 2: x2[32][128] = H @ W2
    const int cg2 = t & 15, ng2 = t >> 4;
    const int c2 = cg2 * 8;    // 8 columns of 128
    const int n2 = ng2 * 2;    // 2 nodes of 32
    float acc2[2][8];
#pragma unroll
    for (int i = 0; i < 2; ++i)
#pragma unroll
        for (int j = 0; j < 8; ++j) acc2[i][j] = 0.f;

#pragma unroll 8
    for (int k = 0; k < F1; ++k) {
        const int nk = n2 ^ (((k >> 3) & 7) << 2);
        const float2 h = *(const float2*)&hT[k][nk];
        const float4 w0 = *(const float4*)&W2[k * F2 + c2];
        const float4 w1 = *(const float4*)&W2[k * F2 + c2 + 4];
        const float hn[2] = {h.x, h.y};
        const float wc[8] = {w0.x, w0.y, w0.z, w0.w, w1.x, w1.y, w1.z, w1.w};
#pragma unroll
        for (int i = 0; i < 2; ++i)
#pragma unroll
            for (int j = 0; j < 8; ++j)
                acc2[i][j] = fmaf(hn[i], wc[j], acc2[i][j]);
    }

#pragma unroll
    for (int i = 0; i < 2; ++i) {
        float* dst = x2 + (size_t)(base + n2 + i) * F2 + c2;
        *(float4*)dst       = make_float4(acc2[i][0], acc2[i][1], acc2[i][2], acc2[i][3]);
        *(float4*)(dst + 4) = make_float4(acc2[i][4], acc2[i][5], acc2[i][6], acc2[i][7]);
    }
}

// one thread per (edge, feature): 128 feats
__global__ void k_scatter2(const float* __restrict__ x2, const float* __restrict__ we,
                           const int* __restrict__ src, const int* __restrict__ dst,
                           float* __restrict__ agg2, unsigned E) {
    unsigned gid = blockIdx.x * 256u + threadIdx.x;
    unsigned e = gid >> 7;
    unsigned d = gid & 127u;
    if (e < E) {
        int s = src[e], t = dst[e];
        atomicAdd(&agg2[(size_t)t * F2 + d], x2[(size_t)s * F2 + d] * we[e]);
    }
}

// one block per graph: dst-scale + leaky + mean pool + 128->64->16 head
__global__ void __launch_bounds__(128) k_pool_head(const float* __restrict__ agg2,
                            const float* __restrict__ dinv_in,
                            const float* __restrict__ Wlin,  // [128][64]
                            const float* __restrict__ Wcls,  // [64][16]
                            float* __restrict__ out) {
    int g = blockIdx.x;
    int t = threadIdx.x;  // 0..127
    __shared__ float p[F2];
    __shared__ float tj[64];
    float acc = 0.f;
    int base = g * NPG;
#pragma unroll 4
    for (int i = 0; i < NPG; ++i) {
        float v = agg2[(size_t)(base + i) * F2 + t] * dinv_in[base + i];
        v = (v >= 0.f) ? v : 0.01f * v;  // leaky
        acc += v;
    }
    p[t] = acc * (1.0f / NPG);
    __syncthreads();
    if (t < 64) {
        float s = 0.f;
#pragma unroll
        for (int d = 0; d < F2; ++d) s = fmaf(p[d], Wlin[d * 64 + t], s);
        tj[t] = s;
    }
    __syncthreads();
    if (t < 16) {
        float s = 0.f;
#pragma unroll
        for (int j = 0; j < 64; ++j) s = fmaf(tj[j], Wcls[j * 16 + t], s);
        out[g * 16 + t] = s;
    }
}

extern "C" void kernel_launch(void* const* d_in, const int* in_sizes, int n_in,
                              void* d_out, int out_size, void* d_ws, size_t ws_size,
                              hipStream_t stream) {
    const float* feats = (const float*)d_in[0];
    const float* we    = (const float*)d_in[1];
    const float* W1    = (const float*)d_in[2];
    const float* W2    = (const float*)d_in[3];
    const float* Wlin  = (const float*)d_in[4];
    const float* Wcls  = (const float*)d_in[5];
    const int*   src   = (const int*)d_in[6];
    const int*   dst   = (const int*)d_in[7];

    const int N = in_sizes[0] / F0;            // 131072
    const unsigned E = (unsigned)in_sizes[1];  // 1048576
    const int G = N / NPG;                     // 1024

    float* out = (float*)d_out;

    // workspace: dinv_out[N] | dinv_in[N] | region1[N*128] | x2[N*128]
    float* dinv_out = (float*)d_ws;
    float* dinv_in  = dinv_out + N;
    float* region1  = dinv_in + N;
    float* agg1     = region1;   // N*64, layer-1 aggregate
    float* agg2     = region1;   // reused as N*128 layer-2 aggregate
    float* x2       = region1 + (size_t)N * F2;

    hipMemsetAsync(dinv_out, 0, (size_t)2 * N * sizeof(float), stream);
    hipMemsetAsync(agg1, 0, (size_t)N * F0 * sizeof(float), stream);

    k_degree<<<(E + 255) / 256, 256, 0, stream>>>(src, dst, dinv_out, dinv_in, (int)E);
    k_finalize_deg<<<(N + 255) / 256, 256, 0, stream>>>(dinv_out, dinv_in, N);

    k_scatter1<<<(unsigned)(((size_t)E * F0 + 255) / 256), 256, 0, stream>>>(
        feats, we, src, dst, dinv_out, agg1, E);

    k_fused2<<<N / BM, 256, 0, stream>>>(agg1, dinv_in, dinv_out, W1, W2, x2);

    hipMemsetAsync(agg2, 0, (size_t)N * F2 * sizeof(float), stream);
    k_scatter2<<<(unsigned)(((size_t)E * F2 + 255) / 256), 256, 0, stream>>>(
        x2, we, src, dst, agg2, E);

    k_pool_head<<<G, 128, 0, stream>>>(agg2, dinv_in, Wlin, Wcls, out);
}

// Round 3
// 894.575 us; speedup vs baseline: 1.7205x; 1.2593x over previous
//
#include <hip/hip_runtime.h>

// 2-layer GCN + mean-pool + linear head for MI355X (gfx950).
// R1: k_fused as node-tiled register-blocked double GEMM (weight reuse).
// R2: atomic scatters (L2 RMW thrash: 524 MB WRITE for a 67 MB target)
//     replaced by CSR-by-dst counting sort + gather; gather2 fused with
//     scale+leaky+mean-pool+head so agg2 is never materialized.

constexpr int NPG = 128;   // nodes per graph
constexpr int F0  = 64;    // in_feats
constexpr int F1  = 256;   // hidden
constexpr int F2  = 128;   // readout
constexpr int BM  = 32;    // nodes per fused block
constexpr int LDA = BM + 4;

constexpr int SC_T = 256;   // scan threads/block
constexpr int SC_E = 1024;  // scan elems/block

__device__ __forceinline__ float leaky(float x) {
    return (x >= 0.f) ? x : 0.01f * x;
}

// ---- CSR build -------------------------------------------------------------

__global__ void k_hist(const int* __restrict__ src, const int* __restrict__ dst,
                       int* __restrict__ cnt_src, int* __restrict__ cnt_dst, unsigned E) {
    unsigned e = blockIdx.x * 256u + threadIdx.x;
    if (e < E) {
        atomicAdd(&cnt_src[src[e]], 1);
        atomicAdd(&cnt_dst[dst[e]], 1);
    }
}

__global__ void k_finalize_deg(const int* __restrict__ cnt_src, const int* __restrict__ cnt_dst,
                               float* __restrict__ dinv_out, float* __restrict__ dinv_in, int N) {
    int i = blockIdx.x * blockDim.x + threadIdx.x;
    if (i < N) {
        dinv_out[i] = rsqrtf((float)max(cnt_src[i], 1));
        dinv_in[i]  = rsqrtf((float)max(cnt_dst[i], 1));
    }
}

// local exclusive scan of 1024 ints per block; block total -> bsum
__global__ void k_scan_local(const int* __restrict__ cnt, int* __restrict__ part,
                             int* __restrict__ bsum, int N) {
    __shared__ int s[SC_T];
    int b = blockIdx.x, t = threadIdx.x;
    int base = b * SC_E + t * 4;
    int v0 = (base + 0 < N) ? cnt[base + 0] : 0;
    int v1 = (base + 1 < N) ? cnt[base + 1] : 0;
    int v2 = (base + 2 < N) ? cnt[base + 2] : 0;
    int v3 = (base + 3 < N) ? cnt[base + 3] : 0;
    int s0 = v0, s1 = s0 + v1, s2 = s1 + v2, s3 = s2 + v3;
    s[t] = s3;
    __syncthreads();
    for (int off = 1; off < SC_T; off <<= 1) {
        int x = (t >= off) ? s[t - off] : 0;
        __syncthreads();
        s[t] += x;
        __syncthreads();
    }
    int excl = t ? s[t - 1] : 0;
    if (base + 0 < N) part[base + 0] = excl;
    if (base + 1 < N) part[base + 1] = excl + s0;
    if (base + 2 < N) part[base + 2] = excl + s1;
    if (base + 3 < N) part[base + 3] = excl + s2;
    if (t == SC_T - 1) bsum[b] = s[t];
}

// single-block exclusive scan of block sums (nb <= 256)
__global__ void k_scan_blocks(int* __restrict__ bsum, int nb) {
    __shared__ int s[256];
    int t = threadIdx.x;
    s[t] = (t < nb) ? bsum[t] : 0;
    __syncthreads();
    for (int off = 1; off < 256; off <<= 1) {
        int x = (t >= off) ? s[t - off] : 0;
        __syncthreads();
        s[t] += x;
        __syncthreads();
    }
    if (t < nb) bsum[t] = t ? s[t - 1] : 0;
}

__global__ void k_scan_add(int* __restrict__ rowptr, const int* __restrict__ bsum,
                           int* __restrict__ cursor, int N, int E) {
    int b = blockIdx.x, t = threadIdx.x;
    int base = b * SC_E + t * 4;
    int off = bsum[b];
#pragma unroll
    for (int j = 0; j < 4; ++j) {
        if (base + j < N) {
            int r = rowptr[base + j] + off;
            rowptr[base + j] = r;
            cursor[base + j] = r;
        }
    }
    if (b == gridDim.x - 1 && t == SC_T - 1) rowptr[N] = E;
}

__global__ void k_fill(const int* __restrict__ src, const int* __restrict__ dst,
                       const float* __restrict__ we, int* __restrict__ cursor,
                       int2* __restrict__ sorted, unsigned E) {
    unsigned e = blockIdx.x * 256u + threadIdx.x;
    if (e < E) {
        int pos = atomicAdd(&cursor[dst[e]], 1);
        sorted[pos] = make_int2(src[e], __float_as_int(we[e]));
    }
}

// ---- layer 1 gather: agg1[n] = dinv_in[n] * sum_e feats[src]*(w*dinv_out[src])
__global__ void __launch_bounds__(256) k_gather1(
        const float* __restrict__ feats, const int* __restrict__ rowptr,
        const int2* __restrict__ sorted, const float* __restrict__ dinv_out,
        const float* __restrict__ dinv_in, float* __restrict__ agg1, int N) {
    int gid = blockIdx.x * 256 + threadIdx.x;
    int n = gid >> 6;
    int d = gid & 63;
    if (n >= N) return;
    int e0 = rowptr[n], e1 = rowptr[n + 1];
    float acc = 0.f;
    for (int e = e0; e < e1; ++e) {
        int2 p = sorted[e];
        float w = __int_as_float(p.y) * dinv_out[p.x];
        acc = fmaf(feats[(size_t)p.x * F0 + d], w, acc);
    }
    agg1[(size_t)n * F0 + d] = acc * dinv_in[n];
}

// ---- fused: x2 = (leaky(agg1 @ W1) * dinv_out) @ W2   (agg1 pre-scaled)
__global__ void __launch_bounds__(256, 2) k_fused2(
        const float* __restrict__ agg1,
        const float* __restrict__ dinv_out,
        const float* __restrict__ W1,   // [64][256]
        const float* __restrict__ W2,   // [256][128]
        float* __restrict__ x2) {
    __shared__ float aT[F0][LDA];
    __shared__ float hT[F1][LDA];
    const int t = threadIdx.x;
    const int base = blockIdx.x * BM;

    {
        const int nn = t >> 3;
        const int f0 = (t & 7) * 8;
        const float4* p = (const float4*)(agg1 + (size_t)(base + nn) * F0 + f0);
        float4 v0 = p[0], v1 = p[1];
        float v[8] = {v0.x, v0.y, v0.z, v0.w, v1.x, v1.y, v1.z, v1.w};
#pragma unroll
        for (int j = 0; j < 8; ++j) {
            int f = f0 + j;
            aT[f][nn ^ (((f >> 3) & 7) << 2)] = v[j];
        }
    }
    __syncthreads();

    const int cg = t & 31, ng = t >> 5;
    const int c0 = cg * 8;
    const int n0 = ng * 4;
    float acc[4][8];
#pragma unroll
    for (int i = 0; i < 4; ++i)
#pragma unroll
        for (int j = 0; j < 8; ++j) acc[i][j] = 0.f;

#pragma unroll 8
    for (int k = 0; k < F0; ++k) {
        const float4 a = *(const float4*)&aT[k][n0 ^ (((k >> 3) & 7) << 2)];
        const float4 w0 = *(const float4*)&W1[k * F1 + c0];
        const float4 w1 = *(const float4*)&W1[k * F1 + c0 + 4];
        const float an[4] = {a.x, a.y, a.z, a.w};
        const float wc[8] = {w0.x, w0.y, w0.z, w0.w, w1.x, w1.y, w1.z, w1.w};
#pragma unroll
        for (int i = 0; i < 4; ++i)
#pragma unroll
            for (int j = 0; j < 8; ++j)
                acc[i][j] = fmaf(an[i], wc[j], acc[i][j]);
    }

    float dsc[4];
#pragma unroll
    for (int i = 0; i < 4; ++i) dsc[i] = dinv_out[base + n0 + i];
#pragma unroll
    for (int j = 0; j < 8; ++j) {
        const int c = c0 + j;
        float4 v;
        v.x = leaky(acc[0][j]) * dsc[0];
        v.y = leaky(acc[1][j]) * dsc[1];
        v.z = leaky(acc[2][j]) * dsc[2];
        v.w = leaky(acc[3][j]) * dsc[3];
        *(float4*)&hT[c][n0 ^ (((c >> 3) & 7) << 2)] = v;
    }
    __syncthreads();

    const int cg2 = t & 15, ng2 = t >> 4;
    const int c2 = cg2 * 8;
    const int n2 = ng2 * 2;
    float acc2[2][8];
#pragma unroll
    for (int i = 0; i < 2; ++i)
#pragma unroll
        for (int j = 0; j < 8; ++j) acc2[i][j] = 0.f;

#pragma unroll 8
    for (int k = 0; k < F1; ++k) {
        const int nk = n2 ^ (((k >> 3) & 7) << 2);
        const float2 h = *(const float2*)&hT[k][nk];
        const float4 w0 = *(const float4*)&W2[k * F2 + c2];
        const float4 w1 = *(const float4*)&W2[k * F2 + c2 + 4];
        const float hn[2] = {h.x, h.y};
        const float wc[8] = {w0.x, w0.y, w0.z, w0.w, w1.x, w1.y, w1.z, w1.w};
#pragma unroll
        for (int i = 0; i < 2; ++i)
#pragma unroll
            for (int j = 0; j < 8; ++j)
                acc2[i][j] = fmaf(hn[i], wc[j], acc2[i][j]);
    }

#pragma unroll
    for (int i = 0; i < 2; ++i) {
        float* dstp = x2 + (size_t)(base + n2 + i) * F2 + c2;
        *(float4*)dstp       = make_float4(acc2[i][0], acc2[i][1], acc2[i][2], acc2[i][3]);
        *(float4*)(dstp + 4) = make_float4(acc2[i][4], acc2[i][5], acc2[i][6], acc2[i][7]);
    }
}

// ---- layer 2 gather + scale + leaky + mean-pool + head, one block per graph
__global__ void __launch_bounds__(256) k_gather2_pool(
        const float* __restrict__ x2, const int* __restrict__ rowptr,
        const int2* __restrict__ sorted, const float* __restrict__ dinv_in,
        const float* __restrict__ Wlin,   // [128][64]
        const float* __restrict__ Wcls,   // [64][16]
        float* __restrict__ out) {
    int g = blockIdx.x;
    int t = threadIdx.x;
    int d = t & 127;
    int half = t >> 7;           // 2 nodes in flight
    __shared__ float pl[2][F2];
    __shared__ float p[F2];
    __shared__ float tj[64];

    float pool = 0.f;
    int nbase = g * NPG;
    for (int i = 0; i < NPG; i += 2) {
        int n = nbase + i + half;
        int e0 = rowptr[n], e1 = rowptr[n + 1];
        float acc = 0.f;
        for (int e = e0; e < e1; ++e) {
            int2 pe = sorted[e];
            acc = fmaf(x2[(size_t)pe.x * F2 + d], __int_as_float(pe.y), acc);
        }
        pool += leaky(acc * dinv_in[n]);
    }
    pl[half][d] = pool;
    __syncthreads();
    if (t < F2) p[t] = (pl[0][t] + pl[1][t]) * (1.0f / NPG);
    __syncthreads();
    if (t < 64) {
        float s = 0.f;
#pragma unroll
        for (int k = 0; k < F2; ++k) s = fmaf(p[k], Wlin[k * 64 + t], s);
        tj[t] = s;
    }
    __syncthreads();
    if (t < 16) {
        float s = 0.f;
#pragma unroll
        for (int j = 0; j < 64; ++j) s = fmaf(tj[j], Wcls[j * 16 + t], s);
        out[g * 16 + t] = s;
    }
}

extern "C" void kernel_launch(void* const* d_in, const int* in_sizes, int n_in,
                              void* d_out, int out_size, void* d_ws, size_t ws_size,
                              hipStream_t stream) {
    const float* feats = (const float*)d_in[0];
    const float* we    = (const float*)d_in[1];
    const float* W1    = (const float*)d_in[2];
    const float* W2    = (const float*)d_in[3];
    const float* Wlin  = (const float*)d_in[4];
    const float* Wcls  = (const float*)d_in[5];
    const int*   src   = (const int*)d_in[6];
    const int*   dst   = (const int*)d_in[7];

    const int N = in_sizes[0] / F0;            // 131072
    const unsigned E = (unsigned)in_sizes[1];  // 1048576
    const int G = N / NPG;                     // 1024

    float* out = (float*)d_out;

    // workspace layout (4-byte units)
    int* ws_i = (int*)d_ws;
    size_t o = 0;
    int* cnt_src = ws_i + o; o += N;           // dead after finalize
    int* cnt_dst = ws_i + o; o += N;           // dead after scan
    int* rowptr  = ws_i + o; o += (size_t)N + 64;
    int* cursor  = ws_i + o; o += N;
    float* dinv_out = (float*)(ws_i + o); o += N;
    float* dinv_in  = (float*)(ws_i + o); o += N;
    int* bsum = ws_i + o; o += 256;
    o = (o + 1) & ~(size_t)1;                  // int2 alignment
    int2* sorted = (int2*)(ws_i + o); o += 2 * (size_t)E;
    float* agg1 = (float*)(ws_i + o); o += (size_t)N * F0;
    float* x2   = (float*)(ws_i + o); o += (size_t)N * F2;
    // total ~112 MB

    hipMemsetAsync(cnt_src, 0, (size_t)2 * N * sizeof(int), stream);

    k_hist<<<(E + 255) / 256, 256, 0, stream>>>(src, dst, cnt_src, cnt_dst, E);
    k_finalize_deg<<<(N + 255) / 256, 256, 0, stream>>>(cnt_src, cnt_dst, dinv_out, dinv_in, N);

    const int nb = (N + SC_E - 1) / SC_E;      // 128
    k_scan_local<<<nb, SC_T, 0, stream>>>(cnt_dst, rowptr, bsum, N);
    k_scan_blocks<<<1, 256, 0, stream>>>(bsum, nb);
    k_scan_add<<<nb, SC_T, 0, stream>>>(rowptr, bsum, cursor, N, (int)E);
    k_fill<<<(E + 255) / 256, 256, 0, stream>>>(src, dst, we, cursor, sorted, E);

    k_gather1<<<(N * 64 + 255) / 256, 256, 0, stream>>>(
        feats, rowptr, sorted, dinv_out, dinv_in, agg1, N);

    k_fused2<<<N / BM, 256, 0, stream>>>(agg1, dinv_out, W1, W2, x2);

    k_gather2_pool<<<G, 256, 0, stream>>>(x2, rowptr, sorted, dinv_in, Wlin, Wcls, out);
}